// Round 13
// baseline (292.291 us; speedup 1.0000x reference)
//
#include <hip/hip_runtime.h>
#include <math.h>

#define B_  16
#define F_  64
#define C_  64
#define M_  512
#define OC_ 32

typedef float vf4 __attribute__((ext_vector_type(4)));   // clang-native for nt st

// ---------------------------------------------------------------------------
// k1: R9 production version (plain x loads, m-split 4-ways). nreps=1 —
// keep it BELOW the fill kernels so k2/k3 own the top-5 this round.
// ---------------------------------------------------------------------------
__global__ __launch_bounds__(128, 6) void k1_mean(
    const float* __restrict__ x,
    float* __restrict__ s_out, float* __restrict__ rpart)
{
    const int gid = blockIdx.x;        // bc*4 + q
    const int q   = gid & 3;
    const int bc  = gid >> 2;
    const int b   = bc >> 6;
    const int c   = bc & 63;
    const int t   = threadIdx.x;
    const int tf  = t >> 5;            // 0..3 -> f chunk
    const int tm  = t & 31;            // float4 column within window
    const int m4  = (q << 5) + tm;     // global float4 index 0..127

    const size_t rowbase = ((size_t)b * F_ * C_ + c) * M_;   // + f*C*M
    float ax = 0.f, ay = 0.f, az = 0.f, aw = 0.f;
    #pragma unroll 8
    for (int j = 0; j < 16; ++j) {
        const int f = (tf << 4) + j;
        const float4 v = ((const float4*)(x + rowbase + (size_t)f * C_ * M_))[m4];
        ax += v.x; ay += v.y; az += v.z; aw += v.w;
    }

    __shared__ float4 red[4][32];
    red[tf][tm] = make_float4(ax, ay, az, aw);
    __syncthreads();

    if (tf == 0) {                     // lanes 0..31 of wave 0
        const float4 r1 = red[1][tm], r2 = red[2][tm], r3 = red[3][tm];
        const float inv_f = 1.0f / (float)F_;
        float4 sv;
        sv.x = (ax + r1.x + r2.x + r3.x) * inv_f;
        sv.y = (ay + r1.y + r2.y + r3.y) * inv_f;
        sv.z = (az + r1.z + r2.z + r3.z) * inv_f;
        sv.w = (aw + r1.w + r2.w + r3.w) * inv_f;
        ((float4*)(s_out + (size_t)bc * M_))[m4] = sv;

        float p = sv.x + sv.y + sv.z + sv.w;
        #pragma unroll
        for (int off = 16; off > 0; off >>= 1) p += __shfl_xor(p, off);
        if (t == 0) rpart[gid] = p;
    }
}

// ---------------------------------------------------------------------------
// k2 diag: R3/R9 structure, stage+reduce repeated nreps=16 (idempotent,
// opaque0==0 defeats CSE). Surfaces k2 in top-5 with FETCH/VALU/occupancy.
// ---------------------------------------------------------------------------
__global__ __launch_bounds__(256) void k2_laplace(
    const float* __restrict__ A, const float* __restrict__ phys,
    const float* __restrict__ kappa_p, const float* __restrict__ alpha_p,
    const float* __restrict__ s_in, const float* __restrict__ rpart,
    const float* __restrict__ w1, const float* __restrict__ b1,
    const float* __restrict__ w2, const float* __restrict__ b2,
    float* __restrict__ snew, int nreps, int opaque0)
{
    __shared__ float Al[C_ * 65];
    __shared__ float sl[C_];
    __shared__ float redD[4 * C_];
    __shared__ float redA[4 * C_];

    const int bm = blockIdx.x;     // b*M + m
    const int b  = bm >> 9;
    const int m  = bm & 511;
    const int t  = threadIdx.x;    // 0..255
    const int c  = t & 63;
    const int q  = t >> 6;

    float r = 0.f;
    if (t < 64) {
        const float4 rp = ((const float4*)rpart)[b * C_ + t];
        const float rin = (rp.x + rp.y + rp.z + rp.w) * (1.0f / (float)M_);
        r = b2[0];
        #pragma unroll
        for (int j = 0; j < 16; ++j) {
            float h = rin * w1[j] + b1[j];        // w1 is (16,1)
            h = (h > 0.f) ? h : (expf(h) - 1.f);  // ELU(alpha=1)
            r += h * w2[j];
        }
        sl[t] = s_in[((size_t)b * C_ + t) * M_ + m];
    }

    const float4* Ap = (const float4*)(A + (size_t)bm * (C_ * C_));

    for (int rep = 0; rep < nreps; ++rep) {
        #pragma unroll
        for (int i = 0; i < 4; ++i) {
            const int idx = t + i * 256 + rep * opaque0;  // runtime 0
            const float4 v = Ap[idx];
            const int row = idx >> 4;
            const int col = (idx & 15) << 2;
            float* dst = &Al[row * 65 + col];
            dst[0] = v.x; dst[1] = v.y; dst[2] = v.z; dst[3] = v.w;
        }
        __syncthreads();

        float dpart = 0.f, apart = 0.f;
        const int j0 = q << 4;
        #pragma unroll
        for (int j = 0; j < 16; ++j) {
            dpart += Al[c * 65 + (j0 + j)];              // row c (deg)
            apart += Al[(j0 + j) * 65 + c] * sl[j0 + j]; // col c (A^T s)
        }
        redD[(q << 6) + c] = dpart;
        redA[(q << 6) + c] = apart;
        __syncthreads();
    }

    if (t < 64) {
        const float deg = redD[t] + redD[64 + t] + redD[128 + t] + redD[192 + t];
        const float As  = redA[t] + redA[64 + t] + redA[128 + t] + redA[192 + t];
        const float sval = sl[t];
        const float k    = log1pf(expf(kappa_p[0]));   // softplus
        const float Ls   = deg * sval - As;
        const float val  = sval - k * Ls
                         + (r + alpha_p[0] * phys[((size_t)b * C_ + t) * M_ + m]);
        snew[((size_t)b * C_ + t) * M_ + m] = val;
    }
}

// ---------------------------------------------------------------------------
// k3 diag: R9 nt-store expansion repeated nreps=10. Every pass re-pays the
// HBM store (nt) -> marginal = true production k3 cost.
// ---------------------------------------------------------------------------
__global__ __launch_bounds__(256) void k3_expand(
    const float* __restrict__ snew,
    const float* __restrict__ pw, const float* __restrict__ pb,
    float* __restrict__ out, int nreps, int opaque0)
{
    const int n4 = (B_ * OC_ * C_ * M_) / 4;   // 4,194,304
    for (int rep = 0; rep < nreps; ++rep) {
        const int ofs = rep * opaque0;         // runtime 0
        for (int i = blockIdx.x * blockDim.x + threadIdx.x; i < n4;
             i += gridDim.x * blockDim.x) {
            const int ii = i + ofs;
            const int m4 = ii & 127;           // M/4 = 128
            const int c  = (ii >> 7) & 63;
            const int o  = (ii >> 13) & 31;
            const int b  = ii >> 18;
            const float4 v = ((const float4*)snew)[(((b << 6) + c) << 7) + m4];
            const float w  = pw[o];
            const float bb = pb[o];
            vf4 r;
            r.x = v.x * w + bb; r.y = v.y * w + bb;
            r.z = v.z * w + bb; r.w = v.w * w + bb;
            __builtin_nontemporal_store(r, ((vf4*)out) + ii);
        }
    }
}

extern "C" void kernel_launch(void* const* d_in, const int* in_sizes, int n_in,
                              void* d_out, int out_size, void* d_ws, size_t ws_size,
                              hipStream_t stream)
{
    const float* x     = (const float*)d_in[0];
    const float* A     = (const float*)d_in[1];
    const float* phys  = (const float*)d_in[2];
    const float* kappa = (const float*)d_in[3];
    const float* alpha = (const float*)d_in[4];
    const float* w1    = (const float*)d_in[5];
    const float* b1    = (const float*)d_in[6];
    const float* w2    = (const float*)d_in[7];
    const float* b2    = (const float*)d_in[8];
    const float* pw    = (const float*)d_in[9];
    const float* pb    = (const float*)d_in[10];
    float* out = (float*)d_out;

    float* ws    = (float*)d_ws;
    float* s     = ws;                            // B*C*M
    float* snew  = ws + (size_t)B_ * C_ * M_;     // B*C*M
    float* rpart = ws + (size_t)2 * B_ * C_ * M_; // B*C*4 (16B-aligned)

    k1_mean<<<B_ * C_ * 4, 128, 0, stream>>>(x, s, rpart);
    k2_laplace<<<B_ * M_, 256, 0, stream>>>(A, phys, kappa, alpha, s, rpart,
                                            w1, b1, w2, b2, snew,
                                            /*nreps=*/16, /*opaque0=*/0);
    k3_expand<<<2048, 256, 0, stream>>>(snew, pw, pb, out,
                                        /*nreps=*/10, /*opaque0=*/0);
}

// Round 14
// 69.902 us; speedup vs baseline: 4.1815x; 4.1815x over previous
//
#include <hip/hip_runtime.h>
#include <math.h>

#define B_  16
#define F_  64
#define C_  64
#define M_  512
#define OC_ 32

typedef float vf4 __attribute__((ext_vector_type(4)));   // clang-native for nt st

// ---------------------------------------------------------------------------
// k1: R9 production version (plain x loads, m-split 4-ways). At its floor
// (R11: 16-pass uniform 17.7 us/pass).
// ---------------------------------------------------------------------------
__global__ __launch_bounds__(128, 6) void k1_mean(
    const float* __restrict__ x,
    float* __restrict__ s_out, float* __restrict__ rpart)
{
    const int gid = blockIdx.x;        // bc*4 + q
    const int q   = gid & 3;
    const int bc  = gid >> 2;
    const int b   = bc >> 6;
    const int c   = bc & 63;
    const int t   = threadIdx.x;
    const int tf  = t >> 5;            // 0..3 -> f chunk
    const int tm  = t & 31;            // float4 column within window
    const int m4  = (q << 5) + tm;     // global float4 index 0..127

    const size_t rowbase = ((size_t)b * F_ * C_ + c) * M_;   // + f*C*M
    float ax = 0.f, ay = 0.f, az = 0.f, aw = 0.f;
    #pragma unroll 8
    for (int j = 0; j < 16; ++j) {
        const int f = (tf << 4) + j;
        const float4 v = ((const float4*)(x + rowbase + (size_t)f * C_ * M_))[m4];
        ax += v.x; ay += v.y; az += v.z; aw += v.w;
    }

    __shared__ float4 red[4][32];
    red[tf][tm] = make_float4(ax, ay, az, aw);
    __syncthreads();

    if (tf == 0) {                     // lanes 0..31 of wave 0
        const float4 r1 = red[1][tm], r2 = red[2][tm], r3 = red[3][tm];
        const float inv_f = 1.0f / (float)F_;
        float4 sv;
        sv.x = (ax + r1.x + r2.x + r3.x) * inv_f;
        sv.y = (ay + r1.y + r2.y + r3.y) * inv_f;
        sv.z = (az + r1.z + r2.z + r3.z) * inv_f;
        sv.w = (aw + r1.w + r2.w + r3.w) * inv_f;
        ((float4*)(s_out + (size_t)bc * M_))[m4] = sv;

        float p = sv.x + sv.y + sv.z + sv.w;
        #pragma unroll
        for (int off = 16; off > 0; off >>= 1) p += __shfl_xor(p, off);
        if (t == 0) rpart[gid] = p;
    }
}

// ---------------------------------------------------------------------------
// k2 v7: async double-buffered tiles via global_load_lds (linear LDS).
// Block = (b, 4-m strip), 256 thr, 2 buffers x 16 KB. Per tile:
//   STAGE(next tile, other buf) -> compute(cur) -> barrier (vmcnt drain
//   lands AFTER compute: fetch hides under compute, not before it).
// As_c = col-c dot (linear reads, bank = c mod 32 -> conflict-free).
// deg[j] from the SAME registers: xor32/16 full-add + R5-verified 16->1
// reduce-scatter butterfly (lane h of wave q ends with deg[16q+h]).
// No ds_writes for A at all (DMA), no row-reads (32-way conflict avoided).
// ---------------------------------------------------------------------------
__device__ __forceinline__ void stage_tile(const float* g, float* l, int w, int lane)
{
    #pragma unroll
    for (int i = 0; i < 4; ++i) {
        const float* gp = g + (((w << 2) + i) << 8) + (lane << 2); // f4 (w*4+i)*64+lane
        float*       lp = l + (((w << 2) + i) << 8);               // wave-uniform base
        __builtin_amdgcn_global_load_lds(
            (const __attribute__((address_space(1))) void*)gp,
            (__attribute__((address_space(3))) void*)lp, 16, 0, 0);
    }
}

__global__ __launch_bounds__(256, 4) void k2_async(
    const float* __restrict__ A, const float* __restrict__ phys,
    const float* __restrict__ kappa_p, const float* __restrict__ alpha_p,
    const float* __restrict__ s_in, const float* __restrict__ rpart,
    const float* __restrict__ w1, const float* __restrict__ b1,
    const float* __restrict__ w2, const float* __restrict__ b2,
    float* __restrict__ snew)
{
    __shared__ float Abuf[2][4096];     // 2 x 16 KB, LINEAR [row][col]
    __shared__ float sl[4 * C_];        // sl[mi*64 + j] = s[b, j, m0+mi]
    __shared__ float redA[2][4 * C_];
    __shared__ float degL[2][C_];

    const int t   = threadIdx.x;
    const int c   = t & 63;
    const int q   = t >> 6;             // wave id
    const int blk = blockIdx.x;         // b*128 + strip
    const int b   = blk >> 7;
    const int m0  = (blk & 127) << 2;
    const int j0  = q << 4;

    const float* Ab = A + (size_t)(b * M_ + m0) * (C_ * C_);

    // issue tile 0 DMA immediately (drains at the prologue barrier)
    stage_tile(Ab, &Abuf[0][0], q, c);

    // prologue: s strip, r-MLP, phys prefetch
    sl[t] = s_in[((size_t)(b * C_ + c)) * M_ + m0 + q];   // (mi=q, j=c)
    const float kcoef = log1pf(expf(kappa_p[0]));         // softplus(kappa)
    const float al    = alpha_p[0];
    float r_c = 0.f;
    float4 ph4 = make_float4(0.f, 0.f, 0.f, 0.f);
    if (t < 64) {
        const float4 rp = ((const float4*)rpart)[b * C_ + t];
        const float rin = (rp.x + rp.y + rp.z + rp.w) * (1.0f / (float)M_);
        r_c = b2[0];
        #pragma unroll
        for (int j = 0; j < 16; ++j) {
            float hh = rin * w1[j] + b1[j];
            hh = (hh > 0.f) ? hh : (expf(hh) - 1.f);      // ELU
            r_c += hh * w2[j];
        }
        ph4 = *(const float4*)(phys + ((size_t)(b * C_ + t)) * M_ + m0);
    }
    __syncthreads();    // tile 0 resident + sl visible

    float out_v[4];
    #pragma unroll
    for (int mi = 0; mi < 4; ++mi) {
        const int cur = mi & 1;
        if (mi < 3) stage_tile(Ab + (size_t)(mi + 1) * (C_ * C_),
                               &Abuf[cur ^ 1][0], q, c);

        // s broadcast preload: sv[k] = s[b, j0+k, m0+mi]
        float sv[16];
        #pragma unroll
        for (int kq = 0; kq < 4; ++kq) {
            const float4 s4 = *(const float4*)&sl[mi * 64 + j0 + (kq << 2)];
            sv[kq * 4 + 0] = s4.x; sv[kq * 4 + 1] = s4.y;
            sv[kq * 4 + 2] = s4.z; sv[kq * 4 + 3] = s4.w;
        }

        // As quarter (conflict-free column reads) + capture for deg
        float v[16];
        float ap = 0.f;
        #pragma unroll
        for (int k = 0; k < 16; ++k) {
            const float a = Abuf[cur][(j0 + k) * 64 + c];
            ap += a * sv[k];
            v[k] = a;
        }

        // deg butterfly: full-add over lane^32, lane^16 ...
        #pragma unroll
        for (int k = 0; k < 16; ++k) v[k] += __shfl_xor(v[k], 32);
        #pragma unroll
        for (int k = 0; k < 16; ++k) v[k] += __shfl_xor(v[k], 16);
        // ... then 16->1 reduce-scatter over h = c&15 (R5-verified pattern)
        const int h = c & 15;
        float e[8];
        #pragma unroll
        for (int kk = 0; kk < 8; ++kk) {
            const float sd = (h & 8) ? v[kk] : v[kk + 8];
            const float rv = __shfl_xor(sd, 8);
            e[kk] = ((h & 8) ? v[kk + 8] : v[kk]) + rv;
        }
        float f2[4];
        #pragma unroll
        for (int kk = 0; kk < 4; ++kk) {
            const float sd = (h & 4) ? e[kk] : e[kk + 4];
            const float rv = __shfl_xor(sd, 4);
            f2[kk] = ((h & 4) ? e[kk + 4] : e[kk]) + rv;
        }
        float g2[2];
        #pragma unroll
        for (int kk = 0; kk < 2; ++kk) {
            const float sd = (h & 2) ? f2[kk] : f2[kk + 2];
            const float rv = __shfl_xor(sd, 2);
            g2[kk] = ((h & 2) ? f2[kk + 2] : f2[kk]) + rv;
        }
        float D;
        {
            const float sd = (h & 1) ? g2[0] : g2[1];
            const float rv = __shfl_xor(sd, 1);
            D = ((h & 1) ? g2[1] : g2[0]) + rv;   // deg[j0 + h]
        }

        redA[cur][(q << 6) + c] = ap;
        if (c < 16) degL[cur][j0 + c] = D;
        __syncthreads();     // drains next-tile DMA + red/deg visible

        if (t < 64) {
            const float As = redA[cur][t] + redA[cur][64 + t]
                           + redA[cur][128 + t] + redA[cur][192 + t];
            const float dg = degL[cur][t];
            const float sval = sl[mi * 64 + t];
            const float pv = (mi == 0) ? ph4.x : (mi == 1) ? ph4.y
                           : (mi == 2) ? ph4.z : ph4.w;
            out_v[mi] = sval - kcoef * (dg * sval - As) + (r_c + al * pv);
        }
    }

    if (t < 64) {
        *(float4*)(snew + ((size_t)(b * C_ + t)) * M_ + m0) =
            make_float4(out_v[0], out_v[1], out_v[2], out_v[3]);
    }
}

// ---------------------------------------------------------------------------
// k3: R9 version — nt float4 stores (proven -9.2 us; out never evicts L3).
// ---------------------------------------------------------------------------
__global__ __launch_bounds__(256) void k3_expand(
    const float* __restrict__ snew,
    const float* __restrict__ pw, const float* __restrict__ pb,
    float* __restrict__ out)
{
    const int n4 = (B_ * OC_ * C_ * M_) / 4;   // 4,194,304
    for (int i = blockIdx.x * blockDim.x + threadIdx.x; i < n4;
         i += gridDim.x * blockDim.x) {
        const int m4 = i & 127;          // M/4 = 128
        const int c  = (i >> 7) & 63;
        const int o  = (i >> 13) & 31;
        const int b  = i >> 18;
        const float4 v = ((const float4*)snew)[(((b << 6) + c) << 7) + m4];
        const float w  = pw[o];
        const float bb = pb[o];
        vf4 r;
        r.x = v.x * w + bb; r.y = v.y * w + bb;
        r.z = v.z * w + bb; r.w = v.w * w + bb;
        __builtin_nontemporal_store(r, ((vf4*)out) + i);
    }
}

extern "C" void kernel_launch(void* const* d_in, const int* in_sizes, int n_in,
                              void* d_out, int out_size, void* d_ws, size_t ws_size,
                              hipStream_t stream)
{
    const float* x     = (const float*)d_in[0];
    const float* A     = (const float*)d_in[1];
    const float* phys  = (const float*)d_in[2];
    const float* kappa = (const float*)d_in[3];
    const float* alpha = (const float*)d_in[4];
    const float* w1    = (const float*)d_in[5];
    const float* b1    = (const float*)d_in[6];
    const float* w2    = (const float*)d_in[7];
    const float* b2    = (const float*)d_in[8];
    const float* pw    = (const float*)d_in[9];
    const float* pb    = (const float*)d_in[10];
    float* out = (float*)d_out;

    float* ws    = (float*)d_ws;
    float* s     = ws;                            // B*C*M
    float* snew  = ws + (size_t)B_ * C_ * M_;     // B*C*M
    float* rpart = ws + (size_t)2 * B_ * C_ * M_; // B*C*4 (16B-aligned)

    k1_mean<<<B_ * C_ * 4, 128, 0, stream>>>(x, s, rpart);
    k2_async<<<B_ * (M_ / 4), 256, 0, stream>>>(A, phys, kappa, alpha, s, rpart,
                                                w1, b1, w2, b2, snew);
    k3_expand<<<2048, 256, 0, stream>>>(snew, pw, pb, out);
}

// Round 15
// 65.237 us; speedup vs baseline: 4.4805x; 1.0715x over previous
//
#include <hip/hip_runtime.h>
#include <math.h>

#define B_  16
#define F_  64
#define C_  64
#define M_  512
#define OC_ 32

typedef float vf4 __attribute__((ext_vector_type(4)));   // clang-native for nt st

// ---------------------------------------------------------------------------
// k1: R9 production version (plain x loads, m-split 4-ways). At its floor
// (R11: 16-pass uniform 17.7 us/pass).
// ---------------------------------------------------------------------------
__global__ __launch_bounds__(128, 6) void k1_mean(
    const float* __restrict__ x,
    float* __restrict__ s_out, float* __restrict__ rpart)
{
    const int gid = blockIdx.x;        // bc*4 + q
    const int q   = gid & 3;
    const int bc  = gid >> 2;
    const int b   = bc >> 6;
    const int c   = bc & 63;
    const int t   = threadIdx.x;
    const int tf  = t >> 5;            // 0..3 -> f chunk
    const int tm  = t & 31;            // float4 column within window
    const int m4  = (q << 5) + tm;     // global float4 index 0..127

    const size_t rowbase = ((size_t)b * F_ * C_ + c) * M_;   // + f*C*M
    float ax = 0.f, ay = 0.f, az = 0.f, aw = 0.f;
    #pragma unroll 8
    for (int j = 0; j < 16; ++j) {
        const int f = (tf << 4) + j;
        const float4 v = ((const float4*)(x + rowbase + (size_t)f * C_ * M_))[m4];
        ax += v.x; ay += v.y; az += v.z; aw += v.w;
    }

    __shared__ float4 red[4][32];
    red[tf][tm] = make_float4(ax, ay, az, aw);
    __syncthreads();

    if (tf == 0) {                     // lanes 0..31 of wave 0
        const float4 r1 = red[1][tm], r2 = red[2][tm], r3 = red[3][tm];
        const float inv_f = 1.0f / (float)F_;
        float4 sv;
        sv.x = (ax + r1.x + r2.x + r3.x) * inv_f;
        sv.y = (ay + r1.y + r2.y + r3.y) * inv_f;
        sv.z = (az + r1.z + r2.z + r3.z) * inv_f;
        sv.w = (aw + r1.w + r2.w + r3.w) * inv_f;
        ((float4*)(s_out + (size_t)bc * M_))[m4] = sv;

        float p = sv.x + sv.y + sv.z + sv.w;
        #pragma unroll
        for (int off = 16; off > 0; off >>= 1) p += __shfl_xor(p, off);
        if (t == 0) rpart[gid] = p;
    }
}

// ---------------------------------------------------------------------------
// k2 v8: DS-pipe-minimized tile kernel. R9 skeleton (per-(b,m) block,
// 256 thr, reg staging, 2 barriers) with:
//  - LINEAR LDS tile, 4x ds_write_b128 per thread (16B-aligned; was 16
//    misaligned b32 with the 65-pad),
//  - col-only As reads (linear: bank = c mod 32, 2 lanes/bank = free),
//  - deg computed from the STAGING REGISTERS (thread t holds rows
//    {a,a+16,a+32,a+48}, a=t>>4, cols 4h..4h+3): 4 row-partials +
//    16-lane shfl_xor reduce (pre-barrier, overlaps other waves' loads),
//    h==0 lanes write 4 deg values. Deletes the 16-read deg pass.
//  - s broadcast via 4 same-address ds_read_b128.
// DS wave-ops per wave ~halved vs R9 -> attacks the ~15us LDS-pipe excess.
// ---------------------------------------------------------------------------
__global__ __launch_bounds__(256) void k2_laplace(
    const float* __restrict__ A, const float* __restrict__ phys,
    const float* __restrict__ kappa_p, const float* __restrict__ alpha_p,
    const float* __restrict__ s_in, const float* __restrict__ rpart,
    const float* __restrict__ w1, const float* __restrict__ b1,
    const float* __restrict__ w2, const float* __restrict__ b2,
    float* __restrict__ snew)
{
    __shared__ float Ab[C_ * C_];      // linear [row j][col c]
    __shared__ float sl[C_];
    __shared__ float redA[4 * C_];
    __shared__ float degL[C_];

    const int bm = blockIdx.x;     // b*M + m
    const int b  = bm >> 9;
    const int m  = bm & 511;
    const int t  = threadIdx.x;    // 0..255
    const int c  = t & 63;
    const int q  = t >> 6;         // wave
    const int h  = t & 15;
    const int a  = t >> 4;         // row-group base 0..15

    // r-MLP preamble + s/phys gather (t<64), overlaps staging below
    float r = 0.f, phv = 0.f;
    if (t < 64) {
        const float4 rp = ((const float4*)rpart)[b * C_ + t];
        const float rin = (rp.x + rp.y + rp.z + rp.w) * (1.0f / (float)M_);
        r = b2[0];
        #pragma unroll
        for (int j = 0; j < 16; ++j) {
            float hh = rin * w1[j] + b1[j];       // w1 is (16,1)
            hh = (hh > 0.f) ? hh : (expf(hh) - 1.f);  // ELU(alpha=1)
            r += hh * w2[j];
        }
        sl[t] = s_in[((size_t)b * C_ + t) * M_ + m];
        phv   = phys[((size_t)b * C_ + t) * M_ + m];
    }

    // ---- stage A tile to registers, then 4x aligned b128 LDS writes ----
    const float4* Ap = (const float4*)(A + (size_t)bm * (C_ * C_));
    const float4 v0 = Ap[t];
    const float4 v1 = Ap[t + 256];
    const float4 v2 = Ap[t + 512];
    const float4 v3 = Ap[t + 768];
    float4* Ab4 = (float4*)Ab;
    Ab4[t]       = v0;                 // rows a      (cols 4h..4h+3)
    Ab4[t + 256] = v1;                 // rows a+16
    Ab4[t + 512] = v2;                 // rows a+32
    Ab4[t + 768] = v3;                 // rows a+48

    // ---- deg from staging registers: 4 row-partials + 16-lane reduce ----
    float p0 = v0.x + v0.y + v0.z + v0.w;
    float p1 = v1.x + v1.y + v1.z + v1.w;
    float p2 = v2.x + v2.y + v2.z + v2.w;
    float p3 = v3.x + v3.y + v3.z + v3.w;
    #pragma unroll
    for (int mk = 1; mk < 16; mk <<= 1) {
        p0 += __shfl_xor(p0, mk);
        p1 += __shfl_xor(p1, mk);
        p2 += __shfl_xor(p2, mk);
        p3 += __shfl_xor(p3, mk);
    }
    if (h == 0) {                      // one lane per 16-segment
        degL[a]      = p0;
        degL[a + 16] = p1;
        degL[a + 32] = p2;
        degL[a + 48] = p3;
    }
    __syncthreads();                   // Ab, sl, degL visible

    // ---- As quarter-dot: wave q covers j = 16q..16q+15, col c ----
    const int j0 = q << 4;
    const float4 s4a = *(const float4*)&sl[j0];        // broadcast reads
    const float4 s4b = *(const float4*)&sl[j0 + 4];
    const float4 s4c = *(const float4*)&sl[j0 + 8];
    const float4 s4d = *(const float4*)&sl[j0 + 12];
    float ap = 0.f;
    ap += Ab[(j0 +  0) * C_ + c] * s4a.x;
    ap += Ab[(j0 +  1) * C_ + c] * s4a.y;
    ap += Ab[(j0 +  2) * C_ + c] * s4a.z;
    ap += Ab[(j0 +  3) * C_ + c] * s4a.w;
    ap += Ab[(j0 +  4) * C_ + c] * s4b.x;
    ap += Ab[(j0 +  5) * C_ + c] * s4b.y;
    ap += Ab[(j0 +  6) * C_ + c] * s4b.z;
    ap += Ab[(j0 +  7) * C_ + c] * s4b.w;
    ap += Ab[(j0 +  8) * C_ + c] * s4c.x;
    ap += Ab[(j0 +  9) * C_ + c] * s4c.y;
    ap += Ab[(j0 + 10) * C_ + c] * s4c.z;
    ap += Ab[(j0 + 11) * C_ + c] * s4c.w;
    ap += Ab[(j0 + 12) * C_ + c] * s4d.x;
    ap += Ab[(j0 + 13) * C_ + c] * s4d.y;
    ap += Ab[(j0 + 14) * C_ + c] * s4d.z;
    ap += Ab[(j0 + 15) * C_ + c] * s4d.w;
    redA[(q << 6) + c] = ap;
    __syncthreads();

    if (t < 64) {
        const float As = redA[t] + redA[64 + t] + redA[128 + t] + redA[192 + t];
        const float dg = degL[t];
        const float sval = sl[t];
        const float k    = log1pf(expf(kappa_p[0]));   // softplus
        const float Ls   = dg * sval - As;
        const float val  = sval - k * Ls + (r + alpha_p[0] * phv);
        snew[((size_t)b * C_ + t) * M_ + m] = val;
    }
}

// ---------------------------------------------------------------------------
// k3: R9 version — nt float4 stores (proven -9.2 us; out never evicts L3).
// ---------------------------------------------------------------------------
__global__ __launch_bounds__(256) void k3_expand(
    const float* __restrict__ snew,
    const float* __restrict__ pw, const float* __restrict__ pb,
    float* __restrict__ out)
{
    const int n4 = (B_ * OC_ * C_ * M_) / 4;   // 4,194,304
    for (int i = blockIdx.x * blockDim.x + threadIdx.x; i < n4;
         i += gridDim.x * blockDim.x) {
        const int m4 = i & 127;          // M/4 = 128
        const int c  = (i >> 7) & 63;
        const int o  = (i >> 13) & 31;
        const int b  = i >> 18;
        const float4 v = ((const float4*)snew)[(((b << 6) + c) << 7) + m4];
        const float w  = pw[o];
        const float bb = pb[o];
        vf4 r;
        r.x = v.x * w + bb; r.y = v.y * w + bb;
        r.z = v.z * w + bb; r.w = v.w * w + bb;
        __builtin_nontemporal_store(r, ((vf4*)out) + i);
    }
}

extern "C" void kernel_launch(void* const* d_in, const int* in_sizes, int n_in,
                              void* d_out, int out_size, void* d_ws, size_t ws_size,
                              hipStream_t stream)
{
    const float* x     = (const float*)d_in[0];
    const float* A     = (const float*)d_in[1];
    const float* phys  = (const float*)d_in[2];
    const float* kappa = (const float*)d_in[3];
    const float* alpha = (const float*)d_in[4];
    const float* w1    = (const float*)d_in[5];
    const float* b1    = (const float*)d_in[6];
    const float* w2    = (const float*)d_in[7];
    const float* b2    = (const float*)d_in[8];
    const float* pw    = (const float*)d_in[9];
    const float* pb    = (const float*)d_in[10];
    float* out = (float*)d_out;

    float* ws    = (float*)d_ws;
    float* s     = ws;                            // B*C*M
    float* snew  = ws + (size_t)B_ * C_ * M_;     // B*C*M
    float* rpart = ws + (size_t)2 * B_ * C_ * M_; // B*C*4 (16B-aligned)

    k1_mean<<<B_ * C_ * 4, 128, 0, stream>>>(x, s, rpart);
    k2_laplace<<<B_ * M_, 256, 0, stream>>>(A, phys, kappa, alpha, s, rpart,
                                            w1, b1, w2, b2, snew);
    k3_expand<<<2048, 256, 0, stream>>>(snew, pw, pb, out);
}